// Round 1
// baseline (35.855 us; speedup 1.0000x reference)
//
#include <hip/hip_runtime.h>

#define BATCH 131072
#define STEPS 100

// One thread owns TWO consecutive batch elements (a and b below).
// All state lives in registers; per step we store one float4 to each of the
// spk2 and mem2 output slabs (fully coalesced 16B/lane).
__global__ __launch_bounds__(256) void snn_lif_kernel(
    const float* __restrict__ x,
    const float* __restrict__ W1, const float* __restrict__ b1,
    const float* __restrict__ W2, const float* __restrict__ b2,
    float* __restrict__ out)
{
    const int tid = blockIdx.x * blockDim.x + threadIdx.x;  // [0, BATCH/2)

    // Tiny parameter arrays: scalar loads, L2-cached broadcast.
    const float w100 = W1[0], w101 = W1[1], w110 = W1[2], w111 = W1[3];
    const float b10  = b1[0], b11  = b1[1];
    const float w200 = W2[0], w201 = W2[1], w210 = W2[2], w211 = W2[3];
    const float b20  = b2[0], b21  = b2[1];

    // x[2*tid][0..1], x[2*tid+1][0..1]
    const float4 xv = reinterpret_cast<const float4*>(x)[tid];

    // cur1 = x @ W1^T + b1  (constant across time, computed once)
    const float c1a0 = xv.x * w100 + xv.y * w101 + b10;
    const float c1a1 = xv.x * w110 + xv.y * w111 + b11;
    const float c1b0 = xv.z * w100 + xv.w * w101 + b10;
    const float c1b1 = xv.z * w110 + xv.w * w111 + b11;

    float m1a0 = 0.f, m1a1 = 0.f, m1b0 = 0.f, m1b1 = 0.f;
    float m2a0 = 0.f, m2a1 = 0.f, m2b0 = 0.f, m2b1 = 0.f;

    float4* __restrict__ spk_out = reinterpret_cast<float4*>(out);
    float4* __restrict__ mem_out =
        reinterpret_cast<float4*>(out + (size_t)STEPS * BATCH * 2);

    const int slab = BATCH / 2;  // float4s per time slab

#pragma unroll 4
    for (int t = 0; t < STEPS; ++t) {
        float r, s1a0, s1a1, s1b0, s1b1;

        // ---- layer-1 LIF (reset from previous mem, integrate, fire) ----
        r = (m1a0 > 1.0f) ? 1.0f : 0.0f;
        m1a0 = 0.99f * m1a0 + c1a0 - r;
        s1a0 = (m1a0 > 1.0f) ? 1.0f : 0.0f;

        r = (m1a1 > 1.0f) ? 1.0f : 0.0f;
        m1a1 = 0.99f * m1a1 + c1a1 - r;
        s1a1 = (m1a1 > 1.0f) ? 1.0f : 0.0f;

        r = (m1b0 > 1.0f) ? 1.0f : 0.0f;
        m1b0 = 0.99f * m1b0 + c1b0 - r;
        s1b0 = (m1b0 > 1.0f) ? 1.0f : 0.0f;

        r = (m1b1 > 1.0f) ? 1.0f : 0.0f;
        m1b1 = 0.99f * m1b1 + c1b1 - r;
        s1b1 = (m1b1 > 1.0f) ? 1.0f : 0.0f;

        // ---- cur2 = spk1 @ W2^T + b2 ----
        const float c2a0 = s1a0 * w200 + s1a1 * w201 + b20;
        const float c2a1 = s1a0 * w210 + s1a1 * w211 + b21;
        const float c2b0 = s1b0 * w200 + s1b1 * w201 + b20;
        const float c2b1 = s1b0 * w210 + s1b1 * w211 + b21;

        // ---- layer-2 LIF ----
        float4 sp;

        r = (m2a0 > 1.0f) ? 1.0f : 0.0f;
        m2a0 = 0.99f * m2a0 + c2a0 - r;
        sp.x = (m2a0 > 1.0f) ? 1.0f : 0.0f;

        r = (m2a1 > 1.0f) ? 1.0f : 0.0f;
        m2a1 = 0.99f * m2a1 + c2a1 - r;
        sp.y = (m2a1 > 1.0f) ? 1.0f : 0.0f;

        r = (m2b0 > 1.0f) ? 1.0f : 0.0f;
        m2b0 = 0.99f * m2b0 + c2b0 - r;
        sp.z = (m2b0 > 1.0f) ? 1.0f : 0.0f;

        r = (m2b1 > 1.0f) ? 1.0f : 0.0f;
        m2b1 = 0.99f * m2b1 + c2b1 - r;
        sp.w = (m2b1 > 1.0f) ? 1.0f : 0.0f;

        const float4 mm = make_float4(m2a0, m2a1, m2b0, m2b1);

        spk_out[(size_t)t * slab + tid] = sp;
        mem_out[(size_t)t * slab + tid] = mm;
    }
}

extern "C" void kernel_launch(void* const* d_in, const int* in_sizes, int n_in,
                              void* d_out, int out_size, void* d_ws, size_t ws_size,
                              hipStream_t stream) {
    const float* x  = (const float*)d_in[0];
    const float* W1 = (const float*)d_in[1];
    const float* b1 = (const float*)d_in[2];
    const float* W2 = (const float*)d_in[3];
    const float* b2 = (const float*)d_in[4];
    float* out = (float*)d_out;

    const int threads = 256;
    const int blocks = (BATCH / 2) / threads;  // 256 blocks
    snn_lif_kernel<<<blocks, threads, 0, stream>>>(x, W1, b1, W2, b2, out);
}